// Round 1
// 276.814 us; speedup vs baseline: 1.0498x; 1.0498x over previous
//
#include <hip/hip_runtime.h>
#include <math.h>

#define WH 16384

typedef __attribute__((ext_vector_type(8))) short short8;   // 8 bf16 (4 VGPRs) MFMA frag
typedef __attribute__((ext_vector_type(4))) float f32x4;    // MFMA accumulator

__device__ __forceinline__ void atomAddF(float* p, float v) {
    __hip_atomic_fetch_add(p, v, __ATOMIC_RELAXED, __HIP_MEMORY_SCOPE_AGENT);
}
// fp32 -> bf16 round-to-nearest-even (integer trick)
__device__ __forceinline__ unsigned short f2bf(float x) {
    unsigned u = __float_as_uint(x);
    u += 0x7fff + ((u >> 16) & 1);
    return (unsigned short)(u >> 16);
}
__device__ __forceinline__ float bf2f(unsigned short h) {
    return __uint_as_float(((unsigned)h) << 16);
}

// ---------------- zero workspace (G + s regions; ws is poisoned 0xAA) --------
__global__ void zero_ws_kernel(float* __restrict__ p, int n) {
    int i = blockIdx.x * 256 + threadIdx.x;
    if (i < n) p[i] = 0.f;
}

// ---------------- pass A: G = X X^T via split-bf16 MFMA, + channel sums s ----
// grid (16 kchunks, 16 n, 2 inp), block 256 (4 waves), 1024 px per block.
// x = hi + lo (bf16 pair); G += Hh Hh^T + Hh Lo^T + Lo Hh^T + Lo Lo^T.
// R4: T14 async-stage split. Old code interleaved load/convert/ds_write per
// float4 with VGPR=88 -> compiler kept only ~2-3 loads in flight -> ~16
// serialized HBM latencies per tile (all counters <20%). Now: (a) whole tile
// loaded into a 16x float4 reg buffer first (16-deep MLP), (b) next tile's
// loads are ISSUED before the MFMA phase so HBM latency hides under ~5k cy
// of compute. vbuf[] only ever indexed by unrolled-constant i (no scratch).
__global__ __launch_bounds__(256, 2) void gram_kernel(
    const float* __restrict__ xR, const float* __restrict__ xT,
    float* __restrict__ G, float* __restrict__ sv) {
    __shared__ unsigned short shi[16384];  // 32 KB
    __shared__ unsigned short slo[16384];  // 32 KB
    const int t = threadIdx.x, w = t >> 6, lane = t & 63;
    const int n = blockIdx.y, inp = blockIdx.z;
    const float* __restrict__ X = (inp ? xT : xR) + (size_t)n * 64 * WH;
    float* __restrict__ Gout = G + (size_t)(inp * 16 + n) * 4096;
    float* __restrict__ Sout = sv + (size_t)(inp * 16 + n) * 64;
    const int pbase = blockIdx.x << 10;

    f32x4 acc0 = {0.f, 0.f, 0.f, 0.f}, acc1 = acc0, acc2 = acc0, acc3 = acc0;
    float srow[16];
#pragma unroll
    for (int i = 0; i < 16; ++i) srow[i] = 0.f;

    const int g2 = lane >> 1, halfo = (lane & 1) << 2;
    const int m15 = lane & 15, q = lane >> 4;
    const int cha = (w << 4) + m15;
    const int ch0 = m15, ch1 = 16 + m15, ch2 = 32 + m15, ch3 = 48 + m15;

    // prologue: issue tile 0's 16 loads into the register buffer
    float4 vbuf[16];
#pragma unroll
    for (int i = 0; i < 16; ++i) {
        const int r = (i << 2) + w;
        vbuf[i] = *(const float4*)(X + (size_t)r * WH + pbase + (lane << 2));
    }

    for (int tile = 0; tile < 4; ++tile) {
        __syncthreads();  // previous tile's frag reads done
        // convert + swizzled LDS write from the reg buffer (waits vmcnt here,
        // which was covered by the previous tile's compute phase)
#pragma unroll
        for (int i = 0; i < 16; ++i) {
            const int r = (i << 2) + w;
            const float4 v = vbuf[i];
            srow[i] += v.x + v.y + v.z + v.w;
            const unsigned short h0 = f2bf(v.x), h1 = f2bf(v.y), h2 = f2bf(v.z), h3 = f2bf(v.w);
            const unsigned short l0 = f2bf(v.x - bf2f(h0)), l1 = f2bf(v.y - bf2f(h1)),
                                 l2 = f2bf(v.z - bf2f(h2)), l3 = f2bf(v.w - bf2f(h3));
            const int a = (r << 8) + ((g2 ^ (r & 31)) << 3) + halfo;
            *(ushort4*)&shi[a] = make_ushort4(h0, h1, h2, h3);
            *(ushort4*)&slo[a] = make_ushort4(l0, l1, l2, l3);
        }
        __syncthreads();
        // issue NEXT tile's loads now -> in flight across the whole MFMA phase
        if (tile < 3) {
            const int p1 = pbase + ((tile + 1) << 8);
#pragma unroll
            for (int i = 0; i < 16; ++i) {
                const int r = (i << 2) + w;
                vbuf[i] = *(const float4*)(X + (size_t)r * WH + p1 + (lane << 2));
            }
        }
        // compute: wave w owns G row-block w; col-blocks 0..3
#pragma unroll
        for (int kk = 0; kk < 8; ++kk) {
            const int grp = (kk << 2) + q;
            const int offa = (cha << 8) + ((grp ^ (cha & 31)) << 3);
            const int off0 = (ch0 << 8) + ((grp ^ (ch0 & 31)) << 3);
            const int off1 = (ch1 << 8) + ((grp ^ (ch1 & 31)) << 3);
            const int off2 = (ch2 << 8) + ((grp ^ (ch2 & 31)) << 3);
            const int off3 = (ch3 << 8) + ((grp ^ (ch3 & 31)) << 3);
            const short8 ah = *(const short8*)&shi[offa];
            const short8 al = *(const short8*)&slo[offa];
            const short8 bh0 = *(const short8*)&shi[off0], bl0 = *(const short8*)&slo[off0];
            const short8 bh1 = *(const short8*)&shi[off1], bl1 = *(const short8*)&slo[off1];
            const short8 bh2 = *(const short8*)&shi[off2], bl2 = *(const short8*)&slo[off2];
            const short8 bh3 = *(const short8*)&shi[off3], bl3 = *(const short8*)&slo[off3];
            acc0 = __builtin_amdgcn_mfma_f32_16x16x32_bf16(ah, bh0, acc0, 0, 0, 0);
            acc0 = __builtin_amdgcn_mfma_f32_16x16x32_bf16(ah, bl0, acc0, 0, 0, 0);
            acc0 = __builtin_amdgcn_mfma_f32_16x16x32_bf16(al, bh0, acc0, 0, 0, 0);
            acc0 = __builtin_amdgcn_mfma_f32_16x16x32_bf16(al, bl0, acc0, 0, 0, 0);
            acc1 = __builtin_amdgcn_mfma_f32_16x16x32_bf16(ah, bh1, acc1, 0, 0, 0);
            acc1 = __builtin_amdgcn_mfma_f32_16x16x32_bf16(ah, bl1, acc1, 0, 0, 0);
            acc1 = __builtin_amdgcn_mfma_f32_16x16x32_bf16(al, bh1, acc1, 0, 0, 0);
            acc1 = __builtin_amdgcn_mfma_f32_16x16x32_bf16(al, bl1, acc1, 0, 0, 0);
            acc2 = __builtin_amdgcn_mfma_f32_16x16x32_bf16(ah, bh2, acc2, 0, 0, 0);
            acc2 = __builtin_amdgcn_mfma_f32_16x16x32_bf16(ah, bl2, acc2, 0, 0, 0);
            acc2 = __builtin_amdgcn_mfma_f32_16x16x32_bf16(al, bh2, acc2, 0, 0, 0);
            acc2 = __builtin_amdgcn_mfma_f32_16x16x32_bf16(al, bl2, acc2, 0, 0, 0);
            acc3 = __builtin_amdgcn_mfma_f32_16x16x32_bf16(ah, bh3, acc3, 0, 0, 0);
            acc3 = __builtin_amdgcn_mfma_f32_16x16x32_bf16(ah, bl3, acc3, 0, 0, 0);
            acc3 = __builtin_amdgcn_mfma_f32_16x16x32_bf16(al, bh3, acc3, 0, 0, 0);
            acc3 = __builtin_amdgcn_mfma_f32_16x16x32_bf16(al, bl3, acc3, 0, 0, 0);
        }
    }
    // epilogue: C/D map (verified m89/m91): col=lane&15, row=quad*4+reg
    const int rb = (w << 4) + (q << 2);
#pragma unroll
    for (int r = 0; r < 4; ++r) {
        atomAddF(&Gout[(rb + r) * 64 + 0 + m15], acc0[r]);
        atomAddF(&Gout[(rb + r) * 64 + 16 + m15], acc1[r]);
        atomAddF(&Gout[(rb + r) * 64 + 32 + m15], acc2[r]);
        atomAddF(&Gout[(rb + r) * 64 + 48 + m15], acc3[r]);
    }
    // channel sums: wave-wide butterfly then 1 atomic per (wave,row)
#pragma unroll
    for (int i = 0; i < 16; ++i) {
        float v = srow[i];
        for (int m = 32; m >= 1; m >>= 1) v += __shfl_xor(v, m, 64);
        if (lane == 0) atomAddF(&Sout[(i << 2) + w], v);
    }
}

// ------- logits + softmax fused: rs = W G W^T + (Ws)b^T + b(Ws)^T + WH bb^T,
//         softmax over the 128 concatenated rows per column, emit att bf16.
__global__ __launch_bounds__(256) void logits_softmax_kernel(
    const float* __restrict__ WR, const float* __restrict__ bR,
    const float* __restrict__ WT, const float* __restrict__ bT,
    const float* __restrict__ G, const float* __restrict__ sv,
    unsigned short* __restrict__ attb) {
    __shared__ float ldsW[4096];
    __shared__ float ldsWt[4096];
    __shared__ float ldsG[4096];
    __shared__ float ldsL[8192];  // logits [128][64]
    __shared__ float ldsS[64], ldsU[64], ldsMx[64], ldsInv[64];
    const int t = threadIdx.x, n = blockIdx.x;
    for (int inp = 0; inp < 2; ++inp) {
        const float* __restrict__ W = inp ? WT : WR;
        const float* __restrict__ b = inp ? bT : bR;
        const float* __restrict__ Gn = G + (size_t)(inp * 16 + n) * 4096;
        const float* __restrict__ sn = sv + (size_t)(inp * 16 + n) * 64;
        __syncthreads();  // protect LDS reuse across inp iterations
#pragma unroll
        for (int m = 0; m < 16; ++m) {
            const int idx = t + (m << 8);
            const float wv = W[idx];
            ldsW[idx] = wv;
            ldsWt[((idx & 63) << 6) + (idx >> 6)] = wv;
            ldsG[idx] = Gn[idx];
        }
        if (t < 64) ldsS[t] = sn[t];
        __syncthreads();
        if (t < 64) {
            float u = 0.f;
            for (int c = 0; c < 64; ++c) u += ldsW[(t << 6) + c] * ldsS[c];
            ldsU[t] = u;  // u = W s
        }
        const int d = t >> 2, e0 = (t & 3) << 4;
        float a[16];
#pragma unroll
        for (int e = 0; e < 16; ++e) a[e] = 0.f;
        for (int c = 0; c < 64; ++c) {
            const float wv = ldsW[(d << 6) + c];
#pragma unroll
            for (int e = 0; e < 16; ++e) a[e] += wv * ldsG[(c << 6) + e0 + e];
        }
        __syncthreads();
#pragma unroll
        for (int e = 0; e < 16; ++e) ldsG[(d << 6) + e0 + e] = a[e];  // M1 = W G
        __syncthreads();
        float r[16];
#pragma unroll
        for (int e = 0; e < 16; ++e) r[e] = 0.f;
        for (int c = 0; c < 64; ++c) {
            const float m1 = ldsG[(d << 6) + c];
#pragma unroll
            for (int e = 0; e < 16; ++e) r[e] += m1 * ldsWt[(c << 6) + e0 + e];
        }
        const float ud = ldsU[d], bd = b[d];
#pragma unroll
        for (int e = 0; e < 16; ++e) {
            const int ee = e0 + e;
            ldsL[((inp << 6) + d) * 64 + ee] =
                r[e] + ud * b[ee] + bd * ldsU[ee] + 16384.f * bd * b[ee];
        }
    }
    __syncthreads();
    if (t < 64) {  // per-column max & sum over 128 rows
        float mx = -1e30f;
        for (int k = 0; k < 128; ++k) mx = fmaxf(mx, ldsL[(k << 6) + t]);
        float s = 0.f;
        for (int k = 0; k < 128; ++k) s += __expf(ldsL[(k << 6) + t] - mx);
        ldsMx[t] = mx;
        ldsInv[t] = 1.f / s;
    }
    __syncthreads();
    unsigned short* __restrict__ an = attb + (size_t)n * 8192;
#pragma unroll
    for (int i = 0; i < 32; ++i) {
        const int idx = (i << 8) + t;
        const int c = idx & 63;
        an[idx] = f2bf(__expf(ldsL[idx] - ldsMx[c]) * ldsInv[c]);
    }
}

// ---------------- pass B: out[n,c,p] = sum_k att[k][c] * [xR;xT][k][p] ------
// grid (64 px-blocks of 256, 16 n), block 256. R4: same T14 stage split as
// gram — issue ALL 40 staging loads (16 XR + 16 XT + 8 att, ~40-deep MLP)
// into reg buffers before any convert/ds_write. Removes the per-iteration
// vmcnt stall AND the k<64 branch (batch A is pure XR, batch B pure XT).
#define FMA4(acc, s, v)        \
    acc.x += (s) * (v).x;      \
    acc.y += (s) * (v).y;      \
    acc.z += (s) * (v).z;      \
    acc.w += (s) * (v).w
__global__ __launch_bounds__(256, 2) void outv_kernel(
    const float* __restrict__ xR, const float* __restrict__ xT,
    const unsigned short* __restrict__ attb, float* __restrict__ out) {
    __shared__ unsigned short lx[32768];  // [128 k][256 px] bf16, 64 KB
    __shared__ unsigned short la[8192];   // [128 k][64 c]  bf16, 16 KB
    const int t = threadIdx.x, w = t >> 6, lane = t & 63;
    const int n = blockIdx.y;
    const int p0 = blockIdx.x << 8;
    const float* __restrict__ XR = xR + (size_t)n * 64 * WH;
    const float* __restrict__ XT = xT + (size_t)n * 64 * WH;
    const unsigned short* __restrict__ an = attb + (size_t)n * 8192;

    // --- issue every staging load first (reg buffers, unrolled-const idx) ---
    float4 va[16], vb[16];
    ushort4 ab[8];
#pragma unroll
    for (int i = 0; i < 16; ++i) {
        const int k = (i << 2) + w;  // 0..63 -> XR
        va[i] = *(const float4*)(XR + (size_t)k * WH + p0 + (lane << 2));
    }
#pragma unroll
    for (int i = 0; i < 16; ++i) {
        const int k = (i << 2) + w;  // +64 -> XT
        vb[i] = *(const float4*)(XT + (size_t)k * WH + p0 + (lane << 2));
    }
#pragma unroll
    for (int i = 0; i < 8; ++i) ab[i] = *(const ushort4*)&an[(i << 10) + (t << 2)];
    // --- convert + LDS write (vmcnt waits amortized across 40 in-flight) ---
#pragma unroll
    for (int i = 0; i < 16; ++i) {
        const int k = (i << 2) + w;
        const float4 v = va[i];
        *(ushort4*)&lx[(k << 8) + (lane << 2)] =
            make_ushort4(f2bf(v.x), f2bf(v.y), f2bf(v.z), f2bf(v.w));
    }
#pragma unroll
    for (int i = 0; i < 16; ++i) {
        const int k = (i << 2) + w + 64;
        const float4 v = vb[i];
        *(ushort4*)&lx[(k << 8) + (lane << 2)] =
            make_ushort4(f2bf(v.x), f2bf(v.y), f2bf(v.z), f2bf(v.w));
    }
#pragma unroll
    for (int i = 0; i < 8; ++i) {
        const int idx = (i << 10) + (t << 2);
        *(ushort4*)&la[idx] = ab[i];
    }
    __syncthreads();

    const int ci = t >> 5;  // c rows 8ci..8ci+7 (att broadcast across 32 lanes)
    const int pj = t & 31;  // px pj*4..+3 and 128+pj*4..+3
    const float4 z4 = make_float4(0.f, 0.f, 0.f, 0.f);
    float4 c00 = z4, c01 = z4, c02 = z4, c03 = z4, c04 = z4, c05 = z4, c06 = z4, c07 = z4;
    float4 c10 = z4, c11 = z4, c12 = z4, c13 = z4, c14 = z4, c15 = z4, c16 = z4, c17 = z4;
#pragma unroll 4
    for (int k = 0; k < 128; ++k) {
        const ushort4 aA = *(const ushort4*)&la[(k << 6) + (ci << 3)];
        const ushort4 aB = *(const ushort4*)&la[(k << 6) + (ci << 3) + 4];
        const ushort4 x0 = *(const ushort4*)&lx[(k << 8) + (pj << 2)];
        const ushort4 x1 = *(const ushort4*)&lx[(k << 8) + 128 + (pj << 2)];
        const float4 v0 = make_float4(bf2f(x0.x), bf2f(x0.y), bf2f(x0.z), bf2f(x0.w));
        const float4 v1 = make_float4(bf2f(x1.x), bf2f(x1.y), bf2f(x1.z), bf2f(x1.w));
        const float a0 = bf2f(aA.x), a1 = bf2f(aA.y), a2 = bf2f(aA.z), a3 = bf2f(aA.w);
        const float a4 = bf2f(aB.x), a5 = bf2f(aB.y), a6 = bf2f(aB.z), a7 = bf2f(aB.w);
        FMA4(c00, a0, v0); FMA4(c10, a0, v1);
        FMA4(c01, a1, v0); FMA4(c11, a1, v1);
        FMA4(c02, a2, v0); FMA4(c12, a2, v1);
        FMA4(c03, a3, v0); FMA4(c13, a3, v1);
        FMA4(c04, a4, v0); FMA4(c14, a4, v1);
        FMA4(c05, a5, v0); FMA4(c15, a5, v1);
        FMA4(c06, a6, v0); FMA4(c16, a6, v1);
        FMA4(c07, a7, v0); FMA4(c17, a7, v1);
    }
    float* __restrict__ on = out + (size_t)n * 64 * WH + p0;
    const int cb = ci << 3;
    const int po = pj << 2;
    *(float4*)(on + (size_t)(cb + 0) * WH + po) = c00;
    *(float4*)(on + (size_t)(cb + 1) * WH + po) = c01;
    *(float4*)(on + (size_t)(cb + 2) * WH + po) = c02;
    *(float4*)(on + (size_t)(cb + 3) * WH + po) = c03;
    *(float4*)(on + (size_t)(cb + 4) * WH + po) = c04;
    *(float4*)(on + (size_t)(cb + 5) * WH + po) = c05;
    *(float4*)(on + (size_t)(cb + 6) * WH + po) = c06;
    *(float4*)(on + (size_t)(cb + 7) * WH + po) = c07;
    *(float4*)(on + (size_t)(cb + 0) * WH + 128 + po) = c10;
    *(float4*)(on + (size_t)(cb + 1) * WH + 128 + po) = c11;
    *(float4*)(on + (size_t)(cb + 2) * WH + 128 + po) = c12;
    *(float4*)(on + (size_t)(cb + 3) * WH + 128 + po) = c13;
    *(float4*)(on + (size_t)(cb + 4) * WH + 128 + po) = c14;
    *(float4*)(on + (size_t)(cb + 5) * WH + 128 + po) = c15;
    *(float4*)(on + (size_t)(cb + 6) * WH + 128 + po) = c16;
    *(float4*)(on + (size_t)(cb + 7) * WH + 128 + po) = c17;
}

extern "C" void kernel_launch(void* const* d_in, const int* in_sizes, int n_in,
                              void* d_out, int out_size, void* d_ws, size_t ws_size,
                              hipStream_t stream) {
    const float* xR = (const float*)d_in[0];
    const float* xT = (const float*)d_in[1];
    const float* WR = (const float*)d_in[2];
    const float* bR = (const float*)d_in[3];
    const float* WT = (const float*)d_in[4];
    const float* bT = (const float*)d_in[5];
    float* out = (float*)d_out;

    // ws: G [2][16][4096] f32 | s [2][16][64] f32 | att bf16 [16][128][64]
    float* ws = (float*)d_ws;
    float* G = ws;
    float* sv = ws + 131072;
    unsigned short* attb = (unsigned short*)(ws + 133120);

    zero_ws_kernel<<<520, 256, 0, stream>>>(ws, 133120);
    gram_kernel<<<dim3(16, 16, 2), 256, 0, stream>>>(xR, xT, G, sv);
    logits_softmax_kernel<<<16, 256, 0, stream>>>(WR, bR, WT, bT, G, sv, attb);
    outv_kernel<<<dim3(64, 16), 256, 0, stream>>>(xR, xT, attb, out);
}

// Round 3
// 246.270 us; speedup vs baseline: 1.1800x; 1.1240x over previous
//
#include <hip/hip_runtime.h>
#include <math.h>

#define WH 16384

typedef __attribute__((ext_vector_type(8))) short short8;   // 8 bf16 (4 VGPRs) MFMA frag
typedef __attribute__((ext_vector_type(4))) float f32x4;    // MFMA accumulator

__device__ __forceinline__ void atomAddF(float* p, float v) {
    __hip_atomic_fetch_add(p, v, __ATOMIC_RELAXED, __HIP_MEMORY_SCOPE_AGENT);
}
// fp32 -> bf16 round-to-nearest-even (integer trick)
__device__ __forceinline__ unsigned short f2bf(float x) {
    unsigned u = __float_as_uint(x);
    u += 0x7fff + ((u >> 16) & 1);
    return (unsigned short)(u >> 16);
}
__device__ __forceinline__ float bf2f(unsigned short h) {
    return __uint_as_float(((unsigned)h) << 16);
}

// ---------------- zero workspace (G + s regions; ws is poisoned 0xAA) --------
__global__ void zero_ws_kernel(float* __restrict__ p, int n) {
    int i = blockIdx.x * 256 + threadIdx.x;
    if (i < n) p[i] = 0.f;
}

// ---------------- pass A: G = X X^T via split-bf16 MFMA, + channel sums s ----
// (unchanged from R4 — improved below outv; re-measure via counters this round)
__global__ __launch_bounds__(256, 2) void gram_kernel(
    const float* __restrict__ xR, const float* __restrict__ xT,
    float* __restrict__ G, float* __restrict__ sv) {
    __shared__ unsigned short shi[16384];  // 32 KB
    __shared__ unsigned short slo[16384];  // 32 KB
    const int t = threadIdx.x, w = t >> 6, lane = t & 63;
    const int n = blockIdx.y, inp = blockIdx.z;
    const float* __restrict__ X = (inp ? xT : xR) + (size_t)n * 64 * WH;
    float* __restrict__ Gout = G + (size_t)(inp * 16 + n) * 4096;
    float* __restrict__ Sout = sv + (size_t)(inp * 16 + n) * 64;
    const int pbase = blockIdx.x << 10;

    f32x4 acc0 = {0.f, 0.f, 0.f, 0.f}, acc1 = acc0, acc2 = acc0, acc3 = acc0;
    float srow[16];
#pragma unroll
    for (int i = 0; i < 16; ++i) srow[i] = 0.f;

    const int g2 = lane >> 1, halfo = (lane & 1) << 2;
    const int m15 = lane & 15, q = lane >> 4;
    const int cha = (w << 4) + m15;
    const int ch0 = m15, ch1 = 16 + m15, ch2 = 32 + m15, ch3 = 48 + m15;

    // prologue: issue tile 0's 16 loads into the register buffer
    float4 vbuf[16];
#pragma unroll
    for (int i = 0; i < 16; ++i) {
        const int r = (i << 2) + w;
        vbuf[i] = *(const float4*)(X + (size_t)r * WH + pbase + (lane << 2));
    }

    for (int tile = 0; tile < 4; ++tile) {
        __syncthreads();  // previous tile's frag reads done
#pragma unroll
        for (int i = 0; i < 16; ++i) {
            const int r = (i << 2) + w;
            const float4 v = vbuf[i];
            srow[i] += v.x + v.y + v.z + v.w;
            const unsigned short h0 = f2bf(v.x), h1 = f2bf(v.y), h2 = f2bf(v.z), h3 = f2bf(v.w);
            const unsigned short l0 = f2bf(v.x - bf2f(h0)), l1 = f2bf(v.y - bf2f(h1)),
                                 l2 = f2bf(v.z - bf2f(h2)), l3 = f2bf(v.w - bf2f(h3));
            const int a = (r << 8) + ((g2 ^ (r & 31)) << 3) + halfo;
            *(ushort4*)&shi[a] = make_ushort4(h0, h1, h2, h3);
            *(ushort4*)&slo[a] = make_ushort4(l0, l1, l2, l3);
        }
        __syncthreads();
        // issue NEXT tile's loads now -> in flight across the whole MFMA phase
        if (tile < 3) {
            const int p1 = pbase + ((tile + 1) << 8);
#pragma unroll
            for (int i = 0; i < 16; ++i) {
                const int r = (i << 2) + w;
                vbuf[i] = *(const float4*)(X + (size_t)r * WH + p1 + (lane << 2));
            }
        }
        // compute: wave w owns G row-block w; col-blocks 0..3
#pragma unroll
        for (int kk = 0; kk < 8; ++kk) {
            const int grp = (kk << 2) + q;
            const int offa = (cha << 8) + ((grp ^ (cha & 31)) << 3);
            const int off0 = (ch0 << 8) + ((grp ^ (ch0 & 31)) << 3);
            const int off1 = (ch1 << 8) + ((grp ^ (ch1 & 31)) << 3);
            const int off2 = (ch2 << 8) + ((grp ^ (ch2 & 31)) << 3);
            const int off3 = (ch3 << 8) + ((grp ^ (ch3 & 31)) << 3);
            const short8 ah = *(const short8*)&shi[offa];
            const short8 al = *(const short8*)&slo[offa];
            const short8 bh0 = *(const short8*)&shi[off0], bl0 = *(const short8*)&slo[off0];
            const short8 bh1 = *(const short8*)&shi[off1], bl1 = *(const short8*)&slo[off1];
            const short8 bh2 = *(const short8*)&shi[off2], bl2 = *(const short8*)&slo[off2];
            const short8 bh3 = *(const short8*)&shi[off3], bl3 = *(const short8*)&slo[off3];
            acc0 = __builtin_amdgcn_mfma_f32_16x16x32_bf16(ah, bh0, acc0, 0, 0, 0);
            acc0 = __builtin_amdgcn_mfma_f32_16x16x32_bf16(ah, bl0, acc0, 0, 0, 0);
            acc0 = __builtin_amdgcn_mfma_f32_16x16x32_bf16(al, bh0, acc0, 0, 0, 0);
            acc0 = __builtin_amdgcn_mfma_f32_16x16x32_bf16(al, bl0, acc0, 0, 0, 0);
            acc1 = __builtin_amdgcn_mfma_f32_16x16x32_bf16(ah, bh1, acc1, 0, 0, 0);
            acc1 = __builtin_amdgcn_mfma_f32_16x16x32_bf16(ah, bl1, acc1, 0, 0, 0);
            acc1 = __builtin_amdgcn_mfma_f32_16x16x32_bf16(al, bh1, acc1, 0, 0, 0);
            acc1 = __builtin_amdgcn_mfma_f32_16x16x32_bf16(al, bl1, acc1, 0, 0, 0);
            acc2 = __builtin_amdgcn_mfma_f32_16x16x32_bf16(ah, bh2, acc2, 0, 0, 0);
            acc2 = __builtin_amdgcn_mfma_f32_16x16x32_bf16(ah, bl2, acc2, 0, 0, 0);
            acc2 = __builtin_amdgcn_mfma_f32_16x16x32_bf16(al, bh2, acc2, 0, 0, 0);
            acc2 = __builtin_amdgcn_mfma_f32_16x16x32_bf16(al, bl2, acc2, 0, 0, 0);
            acc3 = __builtin_amdgcn_mfma_f32_16x16x32_bf16(ah, bh3, acc3, 0, 0, 0);
            acc3 = __builtin_amdgcn_mfma_f32_16x16x32_bf16(ah, bl3, acc3, 0, 0, 0);
            acc3 = __builtin_amdgcn_mfma_f32_16x16x32_bf16(al, bh3, acc3, 0, 0, 0);
            acc3 = __builtin_amdgcn_mfma_f32_16x16x32_bf16(al, bl3, acc3, 0, 0, 0);
        }
    }
    // epilogue: C/D map (verified m89/m91): col=lane&15, row=quad*4+reg
    const int rb = (w << 4) + (q << 2);
#pragma unroll
    for (int r = 0; r < 4; ++r) {
        atomAddF(&Gout[(rb + r) * 64 + 0 + m15], acc0[r]);
        atomAddF(&Gout[(rb + r) * 64 + 16 + m15], acc1[r]);
        atomAddF(&Gout[(rb + r) * 64 + 32 + m15], acc2[r]);
        atomAddF(&Gout[(rb + r) * 64 + 48 + m15], acc3[r]);
    }
#pragma unroll
    for (int i = 0; i < 16; ++i) {
        float v = srow[i];
        for (int m = 32; m >= 1; m >>= 1) v += __shfl_xor(v, m, 64);
        if (lane == 0) atomAddF(&Sout[(i << 2) + w], v);
    }
}

// ------- logits + softmax fused: rs = W G W^T + (Ws)b^T + b(Ws)^T + WH bb^T,
//         softmax over the 128 concatenated rows per column.
// R5: att stored TRANSPOSED in ws: attP[c][128 k] (so outv can read
// [row][k] fragments directly; only the final store index changed).
__global__ __launch_bounds__(256) void logits_softmax_kernel(
    const float* __restrict__ WR, const float* __restrict__ bR,
    const float* __restrict__ WT, const float* __restrict__ bT,
    const float* __restrict__ G, const float* __restrict__ sv,
    unsigned short* __restrict__ attb) {
    __shared__ float ldsW[4096];
    __shared__ float ldsWt[4096];
    __shared__ float ldsG[4096];
    __shared__ float ldsL[8192];  // logits [128][64]
    __shared__ float ldsS[64], ldsU[64], ldsMx[64], ldsInv[64];
    const int t = threadIdx.x, n = blockIdx.x;
    for (int inp = 0; inp < 2; ++inp) {
        const float* __restrict__ W = inp ? WT : WR;
        const float* __restrict__ b = inp ? bT : bR;
        const float* __restrict__ Gn = G + (size_t)(inp * 16 + n) * 4096;
        const float* __restrict__ sn = sv + (size_t)(inp * 16 + n) * 64;
        __syncthreads();  // protect LDS reuse across inp iterations
#pragma unroll
        for (int m = 0; m < 16; ++m) {
            const int idx = t + (m << 8);
            const float wv = W[idx];
            ldsW[idx] = wv;
            ldsWt[((idx & 63) << 6) + (idx >> 6)] = wv;
            ldsG[idx] = Gn[idx];
        }
        if (t < 64) ldsS[t] = sn[t];
        __syncthreads();
        if (t < 64) {
            float u = 0.f;
            for (int c = 0; c < 64; ++c) u += ldsW[(t << 6) + c] * ldsS[c];
            ldsU[t] = u;  // u = W s
        }
        const int d = t >> 2, e0 = (t & 3) << 4;
        float a[16];
#pragma unroll
        for (int e = 0; e < 16; ++e) a[e] = 0.f;
        for (int c = 0; c < 64; ++c) {
            const float wv = ldsW[(d << 6) + c];
#pragma unroll
            for (int e = 0; e < 16; ++e) a[e] += wv * ldsG[(c << 6) + e0 + e];
        }
        __syncthreads();
#pragma unroll
        for (int e = 0; e < 16; ++e) ldsG[(d << 6) + e0 + e] = a[e];  // M1 = W G
        __syncthreads();
        float r[16];
#pragma unroll
        for (int e = 0; e < 16; ++e) r[e] = 0.f;
        for (int c = 0; c < 64; ++c) {
            const float m1 = ldsG[(d << 6) + c];
#pragma unroll
            for (int e = 0; e < 16; ++e) r[e] += m1 * ldsWt[(c << 6) + e0 + e];
        }
        const float ud = ldsU[d], bd = b[d];
#pragma unroll
        for (int e = 0; e < 16; ++e) {
            const int ee = e0 + e;
            ldsL[((inp << 6) + d) * 64 + ee] =
                r[e] + ud * b[ee] + bd * ldsU[ee] + 16384.f * bd * b[ee];
        }
    }
    __syncthreads();
    if (t < 64) {  // per-column max & sum over 128 rows
        float mx = -1e30f;
        for (int k = 0; k < 128; ++k) mx = fmaxf(mx, ldsL[(k << 6) + t]);
        float s = 0.f;
        for (int k = 0; k < 128; ++k) s += __expf(ldsL[(k << 6) + t] - mx);
        ldsMx[t] = mx;
        ldsInv[t] = 1.f / s;
    }
    __syncthreads();
    unsigned short* __restrict__ an = attb + (size_t)n * 8192;
#pragma unroll
    for (int i = 0; i < 32; ++i) {
        const int idx = (i << 8) + t;
        const int k = idx >> 6, c = idx & 63;
        // transposed store: attP[c][k]
        an[(c << 7) + k] = f2bf(__expf(ldsL[idx] - ldsMx[c]) * ldsInv[c]);
    }
}

// ---------------- pass B: out[n,c,p] = sum_k att[k][c] * [xR;xT][k][p] ------
// R5: MFMA version. Old FMA4 loop was VALU-bound (62% VALUBusy, 46us of VALU
// time, MfmaUtil 0). This is a 64x16384x128 GEMM -> 16x16x32 bf16 MFMA.
// Both operands staged [row][k] in LDS:
//   attP[c][128]  -- produced transposed by logits kernel, plain restage
//   lxT[px][128]  -- in-register transpose: thread t owns px=t, loads all
//                    128 k as scalar dwords (per-instr 256B coalesced),
//                    writes its whole bf16 row as 16x b128.
// XOR slot swizzle (slot ^= row&15, 16B granularity) on BOTH write and read
// keeps staging writes ~4-way and frag reads ~2-way (vs 16-way unswizzled).
// Frag mapping = gram's verified pattern: lane&15=row, (lane>>4)*8+e = k.
__global__ __launch_bounds__(256, 2) void outv_kernel(
    const float* __restrict__ xR, const float* __restrict__ xT,
    const unsigned short* __restrict__ attb, float* __restrict__ out) {
    __shared__ unsigned short lxT[32768];  // [256 px][128 k] bf16, 64 KB
    __shared__ unsigned short lsa[8192];   // [64 c][128 k]  bf16, 16 KB
    const int t = threadIdx.x, w = t >> 6, lane = t & 63;
    const int m15 = lane & 15, q = lane >> 4;
    const int n = blockIdx.y;
    const int p0 = blockIdx.x << 8;
    const float* __restrict__ XR = xR + (size_t)n * 64 * WH + p0 + t;
    const float* __restrict__ XT = xT + (size_t)n * 64 * WH + p0 + t;
    const unsigned short* __restrict__ an = attb + (size_t)n * 8192;

    // --- stage attP -> lsa (swizzled) ---
#pragma unroll
    for (int i = 0; i < 8; ++i) {
        const int idx = (i << 10) + (t << 2);  // 4 ushorts: c = idx>>7, ke0 = idx&127
        const ushort4 av = *(const ushort4*)&an[idx];
        const int c = idx >> 7, ke0 = idx & 127;
        const int slot = ke0 >> 3;
        const int wb = (c << 7) + ((slot ^ (c & 15)) << 3) + (ke0 & 7);
        *(ushort4*)&lsa[wb] = av;
    }
    // --- stage X -> lxT (in-register transpose), 4 chunks of 32 k ---
    const int pxm = t & 15;
#pragma unroll
    for (int c4 = 0; c4 < 4; ++c4) {
        const float* __restrict__ base = (c4 < 2) ? XR : XT;
        float v[32];
#pragma unroll
        for (int j = 0; j < 32; ++j)
            v[j] = base[(size_t)((c4 & 1) * 32 + j) * WH];
#pragma unroll
        for (int s = 0; s < 4; ++s) {
            short8 pkt;
#pragma unroll
            for (int e = 0; e < 8; ++e) pkt[e] = (short)f2bf(v[(s << 3) + e]);
            const int slot = (c4 << 2) + s;
            *(short8*)&lxT[(t << 7) + ((slot ^ pxm) << 3)] = pkt;
        }
    }
    __syncthreads();

    // --- compute: wave w owns px tiles nt = 4w..4w+3, all 4 c tiles ---
    f32x4 z = {0.f, 0.f, 0.f, 0.f};
    f32x4 a00 = z, a01 = z, a02 = z, a03 = z;
    f32x4 a10 = z, a11 = z, a12 = z, a13 = z;
    f32x4 a20 = z, a21 = z, a22 = z, a23 = z;
    f32x4 a30 = z, a31 = z, a32 = z, a33 = z;
    const int rA0 = (0 * 16 + m15) << 7, rA1 = (1 * 16 + m15) << 7;
    const int rA2 = (2 * 16 + m15) << 7, rA3 = (3 * 16 + m15) << 7;
    const int rB0 = (((w << 2) + 0) * 16 + m15) << 7;
    const int rB1 = (((w << 2) + 1) * 16 + m15) << 7;
    const int rB2 = (((w << 2) + 2) * 16 + m15) << 7;
    const int rB3 = (((w << 2) + 3) * 16 + m15) << 7;
#pragma unroll
    for (int kg = 0; kg < 4; ++kg) {
        const int sx = (((kg << 2) + q) ^ m15) << 3;
        const short8 A0 = *(const short8*)&lsa[rA0 + sx];
        const short8 A1 = *(const short8*)&lsa[rA1 + sx];
        const short8 A2 = *(const short8*)&lsa[rA2 + sx];
        const short8 A3 = *(const short8*)&lsa[rA3 + sx];
        const short8 B0 = *(const short8*)&lxT[rB0 + sx];
        const short8 B1 = *(const short8*)&lxT[rB1 + sx];
        const short8 B2 = *(const short8*)&lxT[rB2 + sx];
        const short8 B3 = *(const short8*)&lxT[rB3 + sx];
        a00 = __builtin_amdgcn_mfma_f32_16x16x32_bf16(A0, B0, a00, 0, 0, 0);
        a01 = __builtin_amdgcn_mfma_f32_16x16x32_bf16(A0, B1, a01, 0, 0, 0);
        a02 = __builtin_amdgcn_mfma_f32_16x16x32_bf16(A0, B2, a02, 0, 0, 0);
        a03 = __builtin_amdgcn_mfma_f32_16x16x32_bf16(A0, B3, a03, 0, 0, 0);
        a10 = __builtin_amdgcn_mfma_f32_16x16x32_bf16(A1, B0, a10, 0, 0, 0);
        a11 = __builtin_amdgcn_mfma_f32_16x16x32_bf16(A1, B1, a11, 0, 0, 0);
        a12 = __builtin_amdgcn_mfma_f32_16x16x32_bf16(A1, B2, a12, 0, 0, 0);
        a13 = __builtin_amdgcn_mfma_f32_16x16x32_bf16(A1, B3, a13, 0, 0, 0);
        a20 = __builtin_amdgcn_mfma_f32_16x16x32_bf16(A2, B0, a20, 0, 0, 0);
        a21 = __builtin_amdgcn_mfma_f32_16x16x32_bf16(A2, B1, a21, 0, 0, 0);
        a22 = __builtin_amdgcn_mfma_f32_16x16x32_bf16(A2, B2, a22, 0, 0, 0);
        a23 = __builtin_amdgcn_mfma_f32_16x16x32_bf16(A2, B3, a23, 0, 0, 0);
        a30 = __builtin_amdgcn_mfma_f32_16x16x32_bf16(A3, B0, a30, 0, 0, 0);
        a31 = __builtin_amdgcn_mfma_f32_16x16x32_bf16(A3, B1, a31, 0, 0, 0);
        a32 = __builtin_amdgcn_mfma_f32_16x16x32_bf16(A3, B2, a32, 0, 0, 0);
        a33 = __builtin_amdgcn_mfma_f32_16x16x32_bf16(A3, B3, a33, 0, 0, 0);
    }
    // --- epilogue: C/D map col=lane&15 -> px, row=q*4+reg -> c ---
    float* __restrict__ on = out + (size_t)n * 64 * WH + p0;
#define ST(accv, mt, j)                                                          \
    {                                                                            \
        float* bp = on + (size_t)(((mt) << 4) + (q << 2)) * WH +                 \
                    (((w << 2) + (j)) << 4) + m15;                               \
        bp[0] = accv[0];                                                         \
        bp[WH] = accv[1];                                                        \
        bp[2 * WH] = accv[2];                                                    \
        bp[3 * WH] = accv[3];                                                    \
    }
    ST(a00, 0, 0); ST(a01, 0, 1); ST(a02, 0, 2); ST(a03, 0, 3);
    ST(a10, 1, 0); ST(a11, 1, 1); ST(a12, 1, 2); ST(a13, 1, 3);
    ST(a20, 2, 0); ST(a21, 2, 1); ST(a22, 2, 2); ST(a23, 2, 3);
    ST(a30, 3, 0); ST(a31, 3, 1); ST(a32, 3, 2); ST(a33, 3, 3);
#undef ST
}

extern "C" void kernel_launch(void* const* d_in, const int* in_sizes, int n_in,
                              void* d_out, int out_size, void* d_ws, size_t ws_size,
                              hipStream_t stream) {
    const float* xR = (const float*)d_in[0];
    const float* xT = (const float*)d_in[1];
    const float* WR = (const float*)d_in[2];
    const float* bR = (const float*)d_in[3];
    const float* WT = (const float*)d_in[4];
    const float* bT = (const float*)d_in[5];
    float* out = (float*)d_out;

    // ws: G [2][16][4096] f32 | s [2][16][64] f32 | attP bf16 [16][64][128]
    float* ws = (float*)d_ws;
    float* G = ws;
    float* sv = ws + 131072;
    unsigned short* attb = (unsigned short*)(ws + 133120);

    zero_ws_kernel<<<520, 256, 0, stream>>>(ws, 133120);
    gram_kernel<<<dim3(16, 16, 2), 256, 0, stream>>>(xR, xT, G, sv);
    logits_softmax_kernel<<<16, 256, 0, stream>>>(WR, bR, WT, bT, G, sv, attb);
    outv_kernel<<<dim3(64, 16), 256, 0, stream>>>(xR, xT, attb, out);
}